// Round 2
// baseline (7506.090 us; speedup 1.0000x reference)
//
#include <hip/hip_runtime.h>
#include <stdint.h>

#define SS 64
#define BB 64
#define TT 100
#define HOPC 256
#define NFC 256
#define GCC 256
#define ICC 512
#define NC (1.0f/127.0f)
#define CH 4          // chains per block
#define NBLK (64/CH)  // 16 blocks
#define NTHR 512      // 8 waves: lane = (row, g), row=tid>>3, g=tid&7

// f16 weight arena offsets (in halves; same order as inputs 6..19)
#define OFF_FW     0
#define OFF_FWGLU  8192
#define OFF_G1IH   12288
#define OFF_G1HH   36864
#define OFF_GLU1   49152
#define OFF_G2IH   53248
#define OFF_G2HH   77824
#define OFF_GLU2   90112
#define OFF_G3IH   94208
#define OFF_G3HH   118784
#define OFF_GLU3   131072
#define OFF_SKIPD  135168
#define OFF_SKIPG  176128
#define OFF_OUT    192512
#define W_TOTAL    200704
#define XALL_F32   (TT * BB * HOPC)   // 1,638,400 floats

typedef _Float16 f16;
typedef _Float16 h2 __attribute__((ext_vector_type(2)));
union U16 { uint4 u; h2 h[4]; };

#if __has_builtin(__builtin_amdgcn_fdot2)
#define FDOT2(a, b, c) __builtin_amdgcn_fdot2((a), (b), (c), false)
#else
#define FDOT2(a, b, c) ((c) + (float)(a)[0] * (float)(b)[0] + (float)(a)[1] * (float)(b)[1])
#endif

// ---------------- threefry2x32 core (Random123-KAT verified) ----------------
__device__ __forceinline__ uint32_t rotl32(uint32_t x, int r) {
    return (x << r) | (x >> (32 - r));
}

__device__ __forceinline__ void tf2x32(uint32_t k0, uint32_t k1, uint32_t c0, uint32_t c1,
                                       uint32_t& o0, uint32_t& o1) {
    uint32_t k2 = k0 ^ k1 ^ 0x1BD11BDAu;
    uint32_t x0 = c0 + k0, x1 = c1 + k1;
    x0 += x1; x1 = rotl32(x1, 13); x1 ^= x0;
    x0 += x1; x1 = rotl32(x1, 15); x1 ^= x0;
    x0 += x1; x1 = rotl32(x1, 26); x1 ^= x0;
    x0 += x1; x1 = rotl32(x1, 6);  x1 ^= x0;
    x0 += k1; x1 += k2 + 1u;
    x0 += x1; x1 = rotl32(x1, 17); x1 ^= x0;
    x0 += x1; x1 = rotl32(x1, 29); x1 ^= x0;
    x0 += x1; x1 = rotl32(x1, 16); x1 ^= x0;
    x0 += x1; x1 = rotl32(x1, 24); x1 ^= x0;
    x0 += k2; x1 += k0 + 2u;
    x0 += x1; x1 = rotl32(x1, 13); x1 ^= x0;
    x0 += x1; x1 = rotl32(x1, 15); x1 ^= x0;
    x0 += x1; x1 = rotl32(x1, 26); x1 ^= x0;
    x0 += x1; x1 = rotl32(x1, 6);  x1 ^= x0;
    x0 += k0; x1 += k1 + 3u;
    x0 += x1; x1 = rotl32(x1, 17); x1 ^= x0;
    x0 += x1; x1 = rotl32(x1, 29); x1 ^= x0;
    x0 += x1; x1 = rotl32(x1, 16); x1 ^= x0;
    x0 += x1; x1 = rotl32(x1, 24); x1 ^= x0;
    x0 += k1; x1 += k2 + 4u;
    x0 += x1; x1 = rotl32(x1, 13); x1 ^= x0;
    x0 += x1; x1 = rotl32(x1, 15); x1 ^= x0;
    x0 += x1; x1 = rotl32(x1, 26); x1 ^= x0;
    x0 += x1; x1 = rotl32(x1, 6);  x1 ^= x0;
    x0 += k2; x1 += k0 + 5u;
    o0 = x0; o1 = x1;
}

// jax_threefry_partitionable semantics: bits(m) = x0^x1 of block (0, m)
__device__ __forceinline__ float unifP(uint32_t k0, uint32_t k1, uint32_t m) {
    uint32_t o0, o1;
    tf2x32(k0, k1, 0u, m, o0, o1);
    uint32_t bits = o0 ^ o1;
    return __uint_as_float((bits >> 9) | 0x3f800000u) - 1.0f;
}

__device__ __forceinline__ float clipf(float v) { return fminf(1.0f, fmaxf(-1.0f, v)); }
__device__ __forceinline__ float noiseu(float v, float u) {
    return clipf(v + (u - 0.5f) * NC);
}
__device__ __forceinline__ float sigmf(float v) {
    return __fdividef(1.0f, 1.0f + __expf(-v));
}
__device__ __forceinline__ float tanhfast(float x) {
    float ax = fminf(fabsf(x), 15.0f);
    float e = __expf(2.0f * ax);
    float r = __fdividef(e - 1.0f, e + 1.0f);
    return copysignf(r, x);
}

// barrier WITHOUT the vmcnt(0) drain __syncthreads() would emit.
// No barrier in the seq loop needs vmcnt: all global traffic is reg-private
// (xall loads, rSK loads, outp store). lgkmcnt(0) orders the LDS writes.
__device__ __forceinline__ void bar_lds() {
    asm volatile("s_waitcnt lgkmcnt(0)\n\ts_barrier" ::: "memory");
}

// ---------------- DPP 8-lane reduction (VALU-only, no DS pipe) --------------
__device__ __forceinline__ float red8dpp(float v) {
    int t;
    t = __builtin_amdgcn_update_dpp(0, __float_as_int(v), 0xB1, 0xF, 0xF, true);  // quad xor1
    v += __int_as_float(t);
    t = __builtin_amdgcn_update_dpp(0, __float_as_int(v), 0x4E, 0xF, 0xF, true);  // quad xor2
    v += __int_as_float(t);
    t = __builtin_amdgcn_update_dpp(0, __float_as_int(v), 0x141, 0xF, 0xF, true); // half-row mirror
    v += __int_as_float(t);
    return v;   // all 8 lanes of the group hold the sum
}

// ---------------- f16 dot helper ----------------
__device__ __forceinline__ float dotU(const U16& w, const U16& x, float acc) {
#pragma unroll
    for (int i = 0; i < 4; ++i) acc = FDOT2(w.h[i], x.h[i], acc);
    return acc;
}

// ---------------- register weight structs + loaders ----------------
struct WF1  { U16 w[2]; };                        // K=128, NR=1
struct WGRU { U16 wih[6]; U16 whh[3]; U16 glu; }; // 40 VGPRs
struct WSK  { U16 w[10]; };                       // K=320, NR=2
struct WSG  { U16 w[4]; };                        // K=128, NR=2

__device__ __forceinline__ void ldF1(const f16* W, int row, int g, WF1& r) {
    const f16* p = W + row * 128 + g * 16;
    r.w[0].u = *(const uint4*)p;
    r.w[1].u = *(const uint4*)(p + 8);
}
__device__ __forceinline__ void ldF2(const f16* W, int row, int g, U16& r) {
    r.u = *(const uint4*)(W + row * 64 + g * 8);
}
__device__ __forceinline__ void ldGRU(const f16* Wih, const f16* Whh, const f16* Glu,
                                      int row, int g, WGRU& r) {
#pragma unroll
    for (int j = 0; j < 3; ++j) {
        const f16* p = Wih + (row + 64 * j) * 128 + g * 16;
        r.wih[2 * j].u     = *(const uint4*)p;
        r.wih[2 * j + 1].u = *(const uint4*)(p + 8);
        r.whh[j].u = *(const uint4*)(Whh + (row + 64 * j) * 64 + g * 8);
    }
    r.glu.u = *(const uint4*)(Glu + row * 64 + g * 8);
}
__device__ __forceinline__ void ldSK(const f16* W, int row, int g, WSK& r) {
#pragma unroll
    for (int j = 0; j < 2; ++j) {
        const f16* p = W + (row + 64 * j) * 320 + g * 40;
#pragma unroll
        for (int i = 0; i < 5; ++i) r.w[5 * j + i].u = *(const uint4*)(p + 8 * i);
    }
}
__device__ __forceinline__ void ldSG(const f16* W, int row, int g, WSG& r) {
#pragma unroll
    for (int j = 0; j < 2; ++j) {
        const f16* p = W + (row + 64 * j) * 128 + g * 16;
        r.w[2 * j].u     = *(const uint4*)p;
        r.w[2 * j + 1].u = *(const uint4*)(p + 8);
    }
}

// opaque pin: makes the loaded values asm-defined -> cannot be rematerialized
__device__ __forceinline__ void pinU(U16& r) {
    asm volatile("" : "+v"(r.u.x), "+v"(r.u.y), "+v"(r.u.z), "+v"(r.u.w));
}

// ---------------- weight convert to f16 (flat, same layout) ----------------
struct SrcW { const float* p[14]; };

__global__ __launch_bounds__(256) void fargan_cvtw(SrcW s, f16* __restrict__ dst) {
    const int offs[15] = {0, 8192, 12288, 36864, 49152, 53248, 77824, 90112,
                          94208, 118784, 131072, 135168, 176128, 192512, 200704};
    int i = blockIdx.x * 256 + threadIdx.x;
    if (i >= W_TOTAL) return;
    int sgi = 0;
#pragma unroll
    for (int t = 1; t < 14; ++t) sgi += (i >= offs[t]);
    dst[i] = (f16)s.p[sgi][i - offs[sgi]];
}

// ---------------- feature transpose: f[b][c][t] -> fT[t][b][c] ----------------
__global__ __launch_bounds__(256) void fargan_tr(const float* __restrict__ f,
                                                 float* __restrict__ fT) {
    __shared__ float L[64][104];
    int b = blockIdx.x >> 2, c0 = (blockIdx.x & 3) * 64;
    for (int e = threadIdx.x; e < 6400; e += 256) {
        int r = e / 100, col = e - r * 100;
        L[r][col] = f[b * NFC * TT + (c0 + r) * TT + col];
    }
    __syncthreads();
    for (int e = threadIdx.x; e < 6400; e += 256) {
        int t = e >> 6, c = e & 63;
        fT[(t * BB + b) * NFC + c0 + c] = L[c][t];
    }
}

// ---------------- frame input network (fp32) ----------------
__global__ __launch_bounds__(256) void fargan_frame(
    const float* __restrict__ fT, const float* __restrict__ gfeat,
    const float* __restrict__ W1, const float* __restrict__ ib1,
    const float* __restrict__ W2, const float* __restrict__ ib2,
    float* __restrict__ xall)
{
    __shared__ __align__(16) float cat[16][ICC];
    __shared__ __align__(16) float zb[16][ICC];
    const int tid = threadIdx.x;
    const int t = blockIdx.x >> 2;
    const int q = blockIdx.x & 3;

    for (int bb = 0; bb < 16; ++bb) {
        int b = q * 16 + bb;
        for (int c = tid; c < ICC; c += 256) {
            float v = (c < NFC) ? fT[(t * BB + b) * NFC + c]
                                : gfeat[b * GCC + (c - NFC)];
            cat[bb][c] = v;
        }
    }
    __syncthreads();

    {
        int rg = tid & 63, bg = tid >> 6;
        int n0 = rg * 8, bb0 = bg * 4;
        float acc[8][4];
#pragma unroll
        for (int r = 0; r < 8; ++r)
#pragma unroll
            for (int j = 0; j < 4; ++j) acc[r][j] = 0.f;
        for (int k = 0; k < ICC; k += 4) {
            float4 cv[4];
#pragma unroll
            for (int j = 0; j < 4; ++j) cv[j] = *(const float4*)&cat[bb0 + j][k];
#pragma unroll
            for (int r = 0; r < 8; ++r) {
                float4 wv = *(const float4*)&W1[(n0 + r) * ICC + k];
#pragma unroll
                for (int j = 0; j < 4; ++j)
                    acc[r][j] += wv.x * cv[j].x + wv.y * cv[j].y + wv.z * cv[j].z + wv.w * cv[j].w;
            }
        }
#pragma unroll
        for (int r = 0; r < 8; ++r) {
            float bias = ib1[n0 + r];
#pragma unroll
            for (int j = 0; j < 4; ++j)
                zb[bb0 + j][n0 + r] = tanhf(acc[r][j] + bias);
        }
    }
    __syncthreads();

    {
        int rg = tid & 63, bg = tid >> 6;
        int n0 = rg * 4, bb0 = bg * 4;
        float acc[4][4];
#pragma unroll
        for (int r = 0; r < 4; ++r)
#pragma unroll
            for (int j = 0; j < 4; ++j) acc[r][j] = 0.f;
        for (int k = 0; k < ICC; k += 4) {
            float4 cv[4];
#pragma unroll
            for (int j = 0; j < 4; ++j) cv[j] = *(const float4*)&zb[bb0 + j][k];
#pragma unroll
            for (int r = 0; r < 4; ++r) {
                float4 wv = *(const float4*)&W2[(n0 + r) * ICC + k];
#pragma unroll
                for (int j = 0; j < 4; ++j)
                    acc[r][j] += wv.x * cv[j].x + wv.y * cv[j].y + wv.z * cv[j].z + wv.w * cv[j].w;
            }
        }
#pragma unroll
        for (int r = 0; r < 4; ++r) {
            float bias = ib2[n0 + r];
#pragma unroll
            for (int j = 0; j < 4; ++j) {
                int b = q * 16 + bb0 + j;
                xall[(t * BB + b) * HOPC + n0 + r] = acc[r][j] + bias;
            }
        }
    }
}

// ---------------- sequential chain ------------------------------------------
// v3: CH=4 chains per block (16 blocks). Same (row, g=8) lane layout and
// register-resident weights; each barrier-delimited stage now does 4 chains'
// independent work, amortizing the ~1000-cy sync round trip 4x. Keys ping-pong
// (kkb[2][20], computed 2 steps ahead, shared by all chains); uniforms for
// idx+1 generated at 6 sites x 512 lanes spread through the step.
__global__ __launch_bounds__(512, 2) void fargan_seq(
    const float* __restrict__ xall, const f16* __restrict__ wh,
    float* __restrict__ outp)
{
    const int tid = threadIdx.x;
    const int row = tid >> 3;
    const int g = tid & 7;
    const int bg = blockIdx.x;          // chain-group id (CH chains)

    __shared__ __align__(16) f16 XH[CH][128];          // xsub|s3 mirrors
    __shared__ __align__(16) f16 SKXH[CH][320];        // g1|g2|g3|fw|prevN
    __shared__ __align__(16) f16 TWH[CH][64], HNH[CH][64];
    __shared__ __align__(16) f16 SPNH[CH][128], SKVH[CH][128];
    __shared__ __align__(16) f16 HH[2][CH][3][64];     // GRU state f16 (ping-pong)
    __shared__ __align__(16) float Hf[2][CH][3][64];   // GRU state fp32 (ping-pong)
    __shared__ __align__(16) float UNF[2][CH][704];    // uniforms (idx parity)
    __shared__ uint32_t kkb[2][20];                    // keys ping-pong

    // ---- one-time: register weights (pinned)
    WF1 rF1;  ldF1(wh + OFF_FW, row, g, rF1);
    U16 rF2;  ldF2(wh + OFF_FWGLU, row, g, rF2);
    WGRU rG1; ldGRU(wh + OFF_G1IH, wh + OFF_G1HH, wh + OFF_GLU1, row, g, rG1);
    WGRU rG2; ldGRU(wh + OFF_G2IH, wh + OFF_G2HH, wh + OFF_GLU2, row, g, rG2);
    WGRU rG3; ldGRU(wh + OFF_G3IH, wh + OFF_G3HH, wh + OFF_GLU3, row, g, rG3);
    WSG rSG;  ldSG(wh + OFF_SKIPG, row, g, rSG);
    WF1 rOUT; ldF1(wh + OFF_OUT, row, g, rOUT);

    pinU(rF1.w[0]); pinU(rF1.w[1]); pinU(rF2);
#pragma unroll
    for (int j = 0; j < 6; ++j) { pinU(rG1.wih[j]); pinU(rG2.wih[j]); pinU(rG3.wih[j]); }
#pragma unroll
    for (int j = 0; j < 3; ++j) { pinU(rG1.whh[j]); pinU(rG2.whh[j]); pinU(rG3.whh[j]); }
    pinU(rG1.glu); pinU(rG2.glu); pinU(rG3.glu);
#pragma unroll
    for (int j = 0; j < 4; ++j) pinU(rSG.w[j]);
    pinU(rOUT.w[0]); pinU(rOUT.w[1]);

    float prevO[CH], xs_old[CH];
#pragma unroll
    for (int c = 0; c < CH; ++c) { prevO[c] = 0.f; xs_old[c] = 0.f; }

    // ---- init state + keys(0), keys(1)
    if (tid < 256) {
        int c = tid >> 6, r = tid & 63;
#pragma unroll
        for (int i = 0; i < 3; ++i) { Hf[0][c][i][r] = 0.f; HH[0][c][i][r] = (f16)0.f; }
        XH[c][r] = (f16)0.f; XH[c][64 + r] = (f16)0.f;
    }
    if (tid < 10) {
        uint32_t f0, f1; tf2x32(0u, 1u, 0u, 0u, f0, f1);
        uint32_t A, Bv;  tf2x32(f0, f1, 0u, (uint32_t)tid, A, Bv);
        kkb[0][2 * tid] = A; kkb[0][2 * tid + 1] = Bv;
    } else if (tid >= 32 && tid < 42) {
        int i = tid - 32;
        uint32_t f0, f1; tf2x32(0u, 1u, 0u, 1u, f0, f1);
        uint32_t A, Bv;  tf2x32(f0, f1, 0u, (uint32_t)i, A, Bv);
        kkb[1][2 * i] = A; kkb[1][2 * i + 1] = Bv;
    }
    __syncthreads();

    // ---- uniforms for idx 0 (CH*704 slots)
    for (int e = tid; e < CH * 704; e += NTHR) {
        int c2 = (e >= 2112) ? 3 : (e >= 1408) ? 2 : (e >= 704) ? 1 : 0;
        int j2 = e - c2 * 704;
        int sl = j2 >> 6;
        int kx = (sl < 9) ? 2 * sl : 18;
        uint32_t m2 = (sl < 9) ? (uint32_t)((bg * CH + c2) * 64 + (j2 & 63))
                               : (uint32_t)((bg * CH + c2) * 128 + (j2 - 576));
        UNF[0][c2][j2] = unifP(kkb[0][kx], kkb[0][kx + 1], m2);
    }
    __syncthreads();

// one unifP per lane for next step (idx+1); 6 sites x 512 lanes cover CH*704
#define GEN_SITE(SITEI) do {                                                    \
        int id_ = (SITEI) * 512 + tid;                                          \
        if (id_ < CH * 704) {                                                   \
            int c2 = (id_ >= 2112) ? 3 : (id_ >= 1408) ? 2 : (id_ >= 704) ? 1 : 0; \
            int j2 = id_ - c2 * 704;                                            \
            int sl = j2 >> 6;                                                   \
            int kx = (sl < 9) ? 2 * sl : 18;                                    \
            uint32_t m2 = (sl < 9) ? (uint32_t)((bg * CH + c2) * 64 + (j2 & 63))   \
                                   : (uint32_t)((bg * CH + c2) * 128 + (j2 - 576)); \
            UNF[p ^ 1][c2][j2] = unifP(kkb[p ^ 1][kx], kkb[p ^ 1][kx + 1], m2); \
        } } while (0)

    for (int t = 0; t < TT; ++t) {
        for (int s = 0; s < 4; ++s) {
            const int idx = t * 4 + s;
            const int p = idx & 1;       // parity (H state, UNF, kkb)

            // ======== A: input/prev noise + keygen(idx+2)          [barrier 1]
            if (g == 7 && row >= 54) {   // keys for idx+2 into kkb[p] (now dead)
                int i = row - 54;
                uint32_t f0, f1; tf2x32(0u, 1u, 0u, (uint32_t)(idx + 2), f0, f1);
                uint32_t A, Bv;  tf2x32(f0, f1, 0u, (uint32_t)i, A, Bv);
                kkb[p][2 * i] = A; kkb[p][2 * i + 1] = Bv;
            }
            if (g == 0) {
#pragma unroll
                for (int c = 0; c < CH; ++c) {
                    float xv = xall[(t * BB + (bg * CH + c)) * HOPC + s * SS + row];
                    float u0 = UNF[p][c][row];
                    float u1 = UNF[p][c][64 + row];
                    float xs = noiseu(xv, u0);
                    XH[c][row] = (f16)xs; XH[c][64 + row] = (f16)xs_old[c]; xs_old[c] = xs;
                    SKXH[c][256 + row] = (f16)noiseu(prevO[c], u1);
                }
            }
            bar_lds();

            // ======== FW1: tw = tanh(fw_W @ [xsub; s3])            [barrier 2]
            float twv[CH];
#pragma unroll
            for (int c = 0; c < CH; ++c) {
                U16 xa, xb;
                xa.u = *(const uint4*)&XH[c][g * 16];
                xb.u = *(const uint4*)&XH[c][g * 16 + 8];
                float a = dotU(rF1.w[0], xa, 0.f);
                a = dotU(rF1.w[1], xb, a);
                twv[c] = tanhfast(red8dpp(a));
                if (g == 0) TWH[c][row] = (f16)twv[c];
            }
            bar_lds();

            // ======== FW2: fw = noise(tw * sigm(fw_glu @ tw))      [barrier 3]
            {
                U16 xa[CH];
#pragma unroll
                for (int c = 0; c < CH; ++c) xa[c].u = *(const uint4*)&TWH[c][g * 8];
                GEN_SITE(0);
#pragma unroll
                for (int c = 0; c < CH; ++c) {
                    float a = red8dpp(dotU(rF2, xa[c], 0.f));
                    if (g == 0) SKXH[c][192 + row] =
                        (f16)noiseu(twv[c] * sigmf(a), UNF[p][c][128 + row]);
                }
            }
            bar_lds();

            // ======== GRU+GLU x3 (2 barriers each)
#define GRU_STEP(RG, XEXPR, GI, UH, UG, GOFF, PRE1, PRE2)                                   \
            {                                                                               \
                float hNv[CH];                                                              \
                U16 xa[CH], xb[CH], xh[CH];                                                 \
                _Pragma("unroll")                                                           \
                for (int c = 0; c < CH; ++c) {                                              \
                    const f16* xin = (XEXPR);                                               \
                    xa[c].u = *(const uint4*)xin;                                           \
                    xb[c].u = *(const uint4*)(xin + 8);                                     \
                    xh[c].u = *(const uint4*)&HH[p][c][GI][g * 8];                          \
                }                                                                           \
                PRE1;                                                                       \
                _Pragma("unroll")                                                           \
                for (int c = 0; c < CH; ++c) {                                              \
                    float ai0 = 0, ai1 = 0, ai2 = 0, ah0 = 0, ah1 = 0, ah2 = 0;             \
                    ai0 = dotU(RG.wih[0], xa[c], ai0); ai0 = dotU(RG.wih[1], xb[c], ai0);   \
                    ai1 = dotU(RG.wih[2], xa[c], ai1); ai1 = dotU(RG.wih[3], xb[c], ai1);   \
                    ai2 = dotU(RG.wih[4], xa[c], ai2); ai2 = dotU(RG.wih[5], xb[c], ai2);   \
                    ah0 = dotU(RG.whh[0], xh[c], ah0);                                      \
                    ah1 = dotU(RG.whh[1], xh[c], ah1);                                      \
                    ah2 = dotU(RG.whh[2], xh[c], ah2);                                      \
                    ai0 = red8dpp(ai0); ai1 = red8dpp(ai1); ai2 = red8dpp(ai2);             \
                    ah0 = red8dpp(ah0); ah1 = red8dpp(ah1); ah2 = red8dpp(ah2);             \
                    float hold = Hf[p][c][GI][row];                                         \
                    float r  = sigmf(ai0 + ah0);                                            \
                    float z  = sigmf(ai1 + ah1);                                            \
                    float nn = tanhfast(ai2 + r * ah2);                                     \
                    float hnew = (1.f - z) * nn + z * hold;                                 \
                    hNv[c] = noiseu(hnew, UNF[p][c][(UH) + row]);                           \
                    if (g == 0) {                                                           \
                        Hf[p ^ 1][c][GI][row] = hnew;                                       \
                        HH[p ^ 1][c][GI][row] = (f16)hnew;                                  \
                        HNH[c][row] = (f16)hNv[c];                                          \
                    }                                                                       \
                }                                                                           \
                bar_lds();                                                                  \
                PRE2;                                                                       \
                _Pragma("unroll")                                                           \
                for (int c = 0; c < CH; ++c) {                                              \
                    U16 xg; xg.u = *(const uint4*)&HNH[c][g * 8];                           \
                    float ag = red8dpp(dotU(RG.glu, xg, 0.f));                              \
                    if (g == 0) SKXH[c][(GOFF) + row] =                                     \
                        (f16)noiseu(hNv[c] * sigmf(ag), UNF[p][c][(UG) + row]);             \
                }                                                                           \
            }                                                                               \
            bar_lds();

            WSK rSK;
            GRU_STEP(rG1, &SKXH[c][192 + g * 16], 0, 192, 256, 0,
                     GEN_SITE(1), (void)0)
            GRU_STEP(rG2, (g < 4 ? &SKXH[c][g * 16] : &SKXH[c][256 + (g - 4) * 16]),
                     1, 320, 384, 64, GEN_SITE(2), (void)0)
            GRU_STEP(rG3, (g < 4 ? &SKXH[c][64 + g * 16] : &SKXH[c][256 + (g - 4) * 16]),
                     2, 448, 512, 128, GEN_SITE(3),
                     ldSK(wh + OFF_SKIPD, row, g, rSK))   // rSK: GLU3 half, ~1 segment of L2 cover
#undef GRU_STEP

            // ======== SKIP: spN = noise(tanh(skip_dense @ SKXH))   [barrier 10]
            float sp0[CH], sp1[CH];
            {
                GEN_SITE(4);
#pragma unroll
                for (int c = 0; c < CH; ++c) {
                    U16 xs5[5];
#pragma unroll
                    for (int i = 0; i < 5; ++i) xs5[i].u = *(const uint4*)&SKXH[c][g * 40 + 8 * i];
                    float a0 = 0, a1 = 0;
#pragma unroll
                    for (int i = 0; i < 5; ++i) {
                        a0 = dotU(rSK.w[i], xs5[i], a0);
                        a1 = dotU(rSK.w[5 + i], xs5[i], a1);
                    }
                    sp0[c] = noiseu(tanhfast(red8dpp(a0)), UNF[p][c][576 + row]);
                    sp1[c] = noiseu(tanhfast(red8dpp(a1)), UNF[p][c][640 + row]);
                    if (g == 0) { SPNH[c][row] = (f16)sp0[c]; SPNH[c][64 + row] = (f16)sp1[c]; }
                }
            }
            bar_lds();

            // ======== SG: skip = spN * sigm(skip_glu @ spN)        [barrier 11]
            {
                GEN_SITE(5);
#pragma unroll
                for (int c = 0; c < CH; ++c) {
                    U16 xa, xb;
                    xa.u = *(const uint4*)&SPNH[c][g * 16];
                    xb.u = *(const uint4*)&SPNH[c][g * 16 + 8];
                    float a0 = dotU(rSG.w[0], xa, 0.f); a0 = dotU(rSG.w[1], xb, a0);
                    float a1 = dotU(rSG.w[2], xa, 0.f); a1 = dotU(rSG.w[3], xb, a1);
                    a0 = red8dpp(a0); a1 = red8dpp(a1);
                    if (g == 0) {
                        SKVH[c][row]      = (f16)(sp0[c] * sigmf(a0));
                        SKVH[c][64 + row] = (f16)(sp1[c] * sigmf(a1));
                    }
                }
            }
            bar_lds();

            // ======== OUT: o = tanh(out_W @ skip)   [no barrier]
            {
#pragma unroll
                for (int c = 0; c < CH; ++c) {
                    U16 xa, xb;
                    xa.u = *(const uint4*)&SKVH[c][g * 16];
                    xb.u = *(const uint4*)&SKVH[c][g * 16 + 8];
                    float a = dotU(rOUT.w[0], xa, 0.f);
                    a = dotU(rOUT.w[1], xb, a);
                    float o = tanhfast(red8dpp(a));
                    prevO[c] = o;
                    if (g == 0)
                        outp[(bg * CH + c) * (TT * HOPC) + t * HOPC + s * SS + row] = o;
                }
            }
        }
    }
#undef GEN_SITE
}

extern "C" void kernel_launch(void* const* d_in, const int* in_sizes, int n_in,
                              void* d_out, int out_size, void* d_ws, size_t ws_size,
                              hipStream_t stream) {
    const float* features = (const float*)d_in[0];
    const float* gfeat    = (const float*)d_in[1];
    const float* W1       = (const float*)d_in[2];
    const float* ib1      = (const float*)d_in[3];
    const float* W2       = (const float*)d_in[4];
    const float* ib2      = (const float*)d_in[5];

    float* xall = (float*)d_ws;                    // 6.55 MB
    float* fT   = xall + XALL_F32;                 // 6.55 MB
    f16*   wh   = (f16*)(fT + XALL_F32);           // 0.40 MB
    float* outp = (float*)d_out;

    SrcW sw;
    for (int i = 0; i < 14; ++i) sw.p[i] = (const float*)d_in[6 + i];

    hipLaunchKernelGGL(fargan_cvtw, dim3((W_TOTAL + 255) / 256), dim3(256), 0, stream, sw, wh);
    hipLaunchKernelGGL(fargan_tr, dim3(256), dim3(256), 0, stream, features, fT);
    hipLaunchKernelGGL(fargan_frame, dim3(TT * 4), dim3(256), 0, stream,
                       fT, gfeat, W1, ib1, W2, ib2, xall);
    hipLaunchKernelGGL(fargan_seq, dim3(NBLK), dim3(NTHR), 0, stream, xall, wh, outp);
}

// Round 3
// 2692.016 us; speedup vs baseline: 2.7883x; 2.7883x over previous
//
#include <hip/hip_runtime.h>
#include <stdint.h>

#define SS 64
#define BB 64
#define TT 100
#define HOPC 256
#define NFC 256
#define GCC 256
#define ICC 512
#define NC (1.0f/127.0f)
#define NBLK 64       // one block per chain
#define NTHR 512      // 8 waves: lane = (row, g), row=tid>>3, g=tid&7

// f16 weight arena offsets (in halves; same order as inputs 6..19)
#define OFF_FW     0
#define OFF_FWGLU  8192
#define OFF_G1IH   12288
#define OFF_G1HH   36864
#define OFF_GLU1   49152
#define OFF_G2IH   53248
#define OFF_G2HH   77824
#define OFF_GLU2   90112
#define OFF_G3IH   94208
#define OFF_G3HH   118784
#define OFF_GLU3   131072
#define OFF_SKIPD  135168
#define OFF_SKIPG  176128
#define OFF_OUT    192512
#define W_TOTAL    200704
#define XALL_F32   (TT * BB * HOPC)   // 1,638,400 floats

typedef _Float16 f16;
typedef _Float16 h2 __attribute__((ext_vector_type(2)));
union U16 { uint4 u; h2 h[4]; };

#if __has_builtin(__builtin_amdgcn_fdot2)
#define FDOT2(a, b, c) __builtin_amdgcn_fdot2((a), (b), (c), false)
#else
#define FDOT2(a, b, c) ((c) + (float)(a)[0] * (float)(b)[0] + (float)(a)[1] * (float)(b)[1])
#endif

// ---------------- threefry2x32 core (Random123-KAT verified) ----------------
__device__ __forceinline__ uint32_t rotl32(uint32_t x, int r) {
    return (x << r) | (x >> (32 - r));
}

__device__ __forceinline__ void tf2x32(uint32_t k0, uint32_t k1, uint32_t c0, uint32_t c1,
                                       uint32_t& o0, uint32_t& o1) {
    uint32_t k2 = k0 ^ k1 ^ 0x1BD11BDAu;
    uint32_t x0 = c0 + k0, x1 = c1 + k1;
    x0 += x1; x1 = rotl32(x1, 13); x1 ^= x0;
    x0 += x1; x1 = rotl32(x1, 15); x1 ^= x0;
    x0 += x1; x1 = rotl32(x1, 26); x1 ^= x0;
    x0 += x1; x1 = rotl32(x1, 6);  x1 ^= x0;
    x0 += k1; x1 += k2 + 1u;
    x0 += x1; x1 = rotl32(x1, 17); x1 ^= x0;
    x0 += x1; x1 = rotl32(x1, 29); x1 ^= x0;
    x0 += x1; x1 = rotl32(x1, 16); x1 ^= x0;
    x0 += x1; x1 = rotl32(x1, 24); x1 ^= x0;
    x0 += k2; x1 += k0 + 2u;
    x0 += x1; x1 = rotl32(x1, 13); x1 ^= x0;
    x0 += x1; x1 = rotl32(x1, 15); x1 ^= x0;
    x0 += x1; x1 = rotl32(x1, 26); x1 ^= x0;
    x0 += x1; x1 = rotl32(x1, 6);  x1 ^= x0;
    x0 += k0; x1 += k1 + 3u;
    x0 += x1; x1 = rotl32(x1, 17); x1 ^= x0;
    x0 += x1; x1 = rotl32(x1, 29); x1 ^= x0;
    x0 += x1; x1 = rotl32(x1, 16); x1 ^= x0;
    x0 += x1; x1 = rotl32(x1, 24); x1 ^= x0;
    x0 += k1; x1 += k2 + 4u;
    x0 += x1; x1 = rotl32(x1, 13); x1 ^= x0;
    x0 += x1; x1 = rotl32(x1, 15); x1 ^= x0;
    x0 += x1; x1 = rotl32(x1, 26); x1 ^= x0;
    x0 += x1; x1 = rotl32(x1, 6);  x1 ^= x0;
    x0 += k2; x1 += k0 + 5u;
    o0 = x0; o1 = x1;
}

// jax_threefry_partitionable semantics: bits(m) = x0^x1 of block (0, m)
__device__ __forceinline__ float unifP(uint32_t k0, uint32_t k1, uint32_t m) {
    uint32_t o0, o1;
    tf2x32(k0, k1, 0u, m, o0, o1);
    uint32_t bits = o0 ^ o1;
    return __uint_as_float((bits >> 9) | 0x3f800000u) - 1.0f;
}

__device__ __forceinline__ float clipf(float v) { return fminf(1.0f, fmaxf(-1.0f, v)); }
__device__ __forceinline__ float noiseu(float v, float u) {
    return clipf(v + (u - 0.5f) * NC);
}
__device__ __forceinline__ float sigmf(float v) {
    return __fdividef(1.0f, 1.0f + __expf(-v));
}
__device__ __forceinline__ float tanhfast(float x) {
    float ax = fminf(fabsf(x), 15.0f);
    float e = __expf(2.0f * ax);
    float r = __fdividef(e - 1.0f, e + 1.0f);
    return copysignf(r, x);
}

// barrier WITHOUT the vmcnt(0) drain __syncthreads() would emit.
// No barrier in the seq loop needs vmcnt: all global traffic is reg-private
// (xall prefetch, rSK loads, outp store). lgkmcnt(0) orders the LDS writes.
__device__ __forceinline__ void bar_lds() {
    asm volatile("s_waitcnt lgkmcnt(0)\n\ts_barrier" ::: "memory");
}

// ---------------- DPP 8-lane reduction (VALU-only, no DS pipe) --------------
__device__ __forceinline__ float red8dpp(float v) {
    int t;
    t = __builtin_amdgcn_update_dpp(0, __float_as_int(v), 0xB1, 0xF, 0xF, true);  // quad xor1
    v += __int_as_float(t);
    t = __builtin_amdgcn_update_dpp(0, __float_as_int(v), 0x4E, 0xF, 0xF, true);  // quad xor2
    v += __int_as_float(t);
    t = __builtin_amdgcn_update_dpp(0, __float_as_int(v), 0x141, 0xF, 0xF, true); // half-row mirror
    v += __int_as_float(t);
    return v;   // all 8 lanes of the group hold the sum
}

// ---------------- f16 dot helper ----------------
__device__ __forceinline__ float dotU(const U16& w, const U16& x, float acc) {
#pragma unroll
    for (int i = 0; i < 4; ++i) acc = FDOT2(w.h[i], x.h[i], acc);
    return acc;
}

// ---------------- register weight structs + loaders ----------------
struct WF1  { U16 w[2]; };                        // K=128, NR=1
struct WGRU { U16 wih[6]; U16 whh[3]; U16 glu; }; // 40 VGPRs
struct WSK  { U16 w[10]; };                       // K=320, NR=2
struct WSG  { U16 w[4]; };                        // K=128, NR=2

__device__ __forceinline__ void ldF1(const f16* W, int row, int g, WF1& r) {
    const f16* p = W + row * 128 + g * 16;
    r.w[0].u = *(const uint4*)p;
    r.w[1].u = *(const uint4*)(p + 8);
}
__device__ __forceinline__ void ldF2(const f16* W, int row, int g, U16& r) {
    r.u = *(const uint4*)(W + row * 64 + g * 8);
}
__device__ __forceinline__ void ldGRU(const f16* Wih, const f16* Whh, const f16* Glu,
                                      int row, int g, WGRU& r) {
#pragma unroll
    for (int j = 0; j < 3; ++j) {
        const f16* p = Wih + (row + 64 * j) * 128 + g * 16;
        r.wih[2 * j].u     = *(const uint4*)p;
        r.wih[2 * j + 1].u = *(const uint4*)(p + 8);
        r.whh[j].u = *(const uint4*)(Whh + (row + 64 * j) * 64 + g * 8);
    }
    r.glu.u = *(const uint4*)(Glu + row * 64 + g * 8);
}
__device__ __forceinline__ void ldSK(const f16* W, int row, int g, WSK& r) {
#pragma unroll
    for (int j = 0; j < 2; ++j) {
        const f16* p = W + (row + 64 * j) * 320 + g * 40;
#pragma unroll
        for (int i = 0; i < 5; ++i) r.w[5 * j + i].u = *(const uint4*)(p + 8 * i);
    }
}
__device__ __forceinline__ void ldSG(const f16* W, int row, int g, WSG& r) {
#pragma unroll
    for (int j = 0; j < 2; ++j) {
        const f16* p = W + (row + 64 * j) * 128 + g * 16;
        r.w[2 * j].u     = *(const uint4*)p;
        r.w[2 * j + 1].u = *(const uint4*)(p + 8);
    }
}

// opaque pin: makes the loaded values asm-defined -> cannot be rematerialized
__device__ __forceinline__ void pinU(U16& r) {
    asm volatile("" : "+v"(r.u.x), "+v"(r.u.y), "+v"(r.u.z), "+v"(r.u.w));
}

// ---------------- weight convert to f16 (flat, same layout) ----------------
struct SrcW { const float* p[14]; };

__global__ __launch_bounds__(256) void fargan_cvtw(SrcW s, f16* __restrict__ dst) {
    const int offs[15] = {0, 8192, 12288, 36864, 49152, 53248, 77824, 90112,
                          94208, 118784, 131072, 135168, 176128, 192512, 200704};
    int i = blockIdx.x * 256 + threadIdx.x;
    if (i >= W_TOTAL) return;
    int sgi = 0;
#pragma unroll
    for (int t = 1; t < 14; ++t) sgi += (i >= offs[t]);
    dst[i] = (f16)s.p[sgi][i - offs[sgi]];
}

// ---------------- feature transpose: f[b][c][t] -> fT[t][b][c] ----------------
__global__ __launch_bounds__(256) void fargan_tr(const float* __restrict__ f,
                                                 float* __restrict__ fT) {
    __shared__ float L[64][104];
    int b = blockIdx.x >> 2, c0 = (blockIdx.x & 3) * 64;
    for (int e = threadIdx.x; e < 6400; e += 256) {
        int r = e / 100, col = e - r * 100;
        L[r][col] = f[b * NFC * TT + (c0 + r) * TT + col];
    }
    __syncthreads();
    for (int e = threadIdx.x; e < 6400; e += 256) {
        int t = e >> 6, c = e & 63;
        fT[(t * BB + b) * NFC + c0 + c] = L[c][t];
    }
}

// ---------------- frame input network (fp32) ----------------
__global__ __launch_bounds__(256) void fargan_frame(
    const float* __restrict__ fT, const float* __restrict__ gfeat,
    const float* __restrict__ W1, const float* __restrict__ ib1,
    const float* __restrict__ W2, const float* __restrict__ ib2,
    float* __restrict__ xall)
{
    __shared__ __align__(16) float cat[16][ICC];
    __shared__ __align__(16) float zb[16][ICC];
    const int tid = threadIdx.x;
    const int t = blockIdx.x >> 2;
    const int q = blockIdx.x & 3;

    for (int bb = 0; bb < 16; ++bb) {
        int b = q * 16 + bb;
        for (int c = tid; c < ICC; c += 256) {
            float v = (c < NFC) ? fT[(t * BB + b) * NFC + c]
                                : gfeat[b * GCC + (c - NFC)];
            cat[bb][c] = v;
        }
    }
    __syncthreads();

    {
        int rg = tid & 63, bg = tid >> 6;
        int n0 = rg * 8, bb0 = bg * 4;
        float acc[8][4];
#pragma unroll
        for (int r = 0; r < 8; ++r)
#pragma unroll
            for (int j = 0; j < 4; ++j) acc[r][j] = 0.f;
        for (int k = 0; k < ICC; k += 4) {
            float4 cv[4];
#pragma unroll
            for (int j = 0; j < 4; ++j) cv[j] = *(const float4*)&cat[bb0 + j][k];
#pragma unroll
            for (int r = 0; r < 8; ++r) {
                float4 wv = *(const float4*)&W1[(n0 + r) * ICC + k];
#pragma unroll
                for (int j = 0; j < 4; ++j)
                    acc[r][j] += wv.x * cv[j].x + wv.y * cv[j].y + wv.z * cv[j].z + wv.w * cv[j].w;
            }
        }
#pragma unroll
        for (int r = 0; r < 8; ++r) {
            float bias = ib1[n0 + r];
#pragma unroll
            for (int j = 0; j < 4; ++j)
                zb[bb0 + j][n0 + r] = tanhf(acc[r][j] + bias);
        }
    }
    __syncthreads();

    {
        int rg = tid & 63, bg = tid >> 6;
        int n0 = rg * 4, bb0 = bg * 4;
        float acc[4][4];
#pragma unroll
        for (int r = 0; r < 4; ++r)
#pragma unroll
            for (int j = 0; j < 4; ++j) acc[r][j] = 0.f;
        for (int k = 0; k < ICC; k += 4) {
            float4 cv[4];
#pragma unroll
            for (int j = 0; j < 4; ++j) cv[j] = *(const float4*)&zb[bb0 + j][k];
#pragma unroll
            for (int r = 0; r < 4; ++r) {
                float4 wv = *(const float4*)&W2[(n0 + r) * ICC + k];
#pragma unroll
                for (int j = 0; j < 4; ++j)
                    acc[r][j] += wv.x * cv[j].x + wv.y * cv[j].y + wv.z * cv[j].z + wv.w * cv[j].w;
            }
        }
#pragma unroll
        for (int r = 0; r < 4; ++r) {
            float bias = ib2[n0 + r];
#pragma unroll
            for (int j = 0; j < 4; ++j) {
                int b = q * 16 + bb0 + j;
                xall[(t * BB + b) * HOPC + n0 + r] = acc[r][j] + bias;
            }
        }
    }
}

// ---------------- sequential chain ------------------------------------------
// v4 = v2 (CH=1) with the register cap LIFTED: __launch_bounds__(512) only.
// v2's __launch_bounds__(512,2) capped VGPRs at 128 while the pinned weights
// alone need 156 -> everything "register-resident" was scratch-spilled and
// reloaded from L2 in every segment. With 64 blocks on 256 CUs only one block
// per CU ever resides, so the min-occupancy request bought nothing.
__global__ __launch_bounds__(512) void fargan_seq(
    const float* __restrict__ xall, const f16* __restrict__ wh,
    float* __restrict__ outp)
{
    const int tid = threadIdx.x;
    const int row = tid >> 3;
    const int g = tid & 7;
    const int bg = blockIdx.x;          // chain id

    __shared__ __align__(16) f16 XH[128];          // xsub|s3 mirrors
    __shared__ __align__(16) f16 SKXH[320];        // g1|g2|g3|fw|prevN
    __shared__ __align__(16) f16 TWH[64], HNH[64];
    __shared__ __align__(16) f16 SPNH[128], SKVH[128];
    __shared__ __align__(16) f16 HH[2][3][64];     // GRU state f16 mirrors (ping-pong)
    __shared__ __align__(16) float Hf[2][3][64];   // GRU state fp32 (ping-pong)
    __shared__ __align__(16) float UNF[2][704];    // uniforms, double-buffered by idx&1
    __shared__ uint32_t KK[401][20];               // all fold_in keys, all idx

    // ---- one-time: register weights (pinned) + init
    WF1 rF1;  ldF1(wh + OFF_FW, row, g, rF1);
    U16 rF2;  ldF2(wh + OFF_FWGLU, row, g, rF2);
    WGRU rG1; ldGRU(wh + OFF_G1IH, wh + OFF_G1HH, wh + OFF_GLU1, row, g, rG1);
    WGRU rG2; ldGRU(wh + OFF_G2IH, wh + OFF_G2HH, wh + OFF_GLU2, row, g, rG2);
    WGRU rG3; ldGRU(wh + OFF_G3IH, wh + OFF_G3HH, wh + OFF_GLU3, row, g, rG3);
    WSG rSG;  ldSG(wh + OFF_SKIPG, row, g, rSG);
    WF1 rOUT; ldF1(wh + OFF_OUT, row, g, rOUT);

    pinU(rF1.w[0]); pinU(rF1.w[1]); pinU(rF2);
#pragma unroll
    for (int j = 0; j < 6; ++j) { pinU(rG1.wih[j]); pinU(rG2.wih[j]); pinU(rG3.wih[j]); }
#pragma unroll
    for (int j = 0; j < 3; ++j) { pinU(rG1.whh[j]); pinU(rG2.whh[j]); pinU(rG3.whh[j]); }
    pinU(rG1.glu); pinU(rG2.glu); pinU(rG3.glu);
#pragma unroll
    for (int j = 0; j < 4; ++j) pinU(rSG.w[j]);
    pinU(rOUT.w[0]); pinU(rOUT.w[1]);

    float prevO = 0.f, xs_old = 0.f;
    if (g == 0) {
#pragma unroll
        for (int i = 0; i < 3; ++i) { Hf[0][i][row] = 0.f; HH[0][i][row] = (f16)0.f; }
        XH[row] = (f16)0.f; XH[64 + row] = (f16)0.f;
    }

    // ---- prologue: ALL keys for ALL idx (401 x 10 pairs), once (~1 us)
    for (int e = tid; e < 4010; e += NTHR) {
        int ii = e / 10, ki = e - ii * 10;
        uint32_t f0, f1; tf2x32(0u, 1u, 0u, (uint32_t)ii, f0, f1);
        uint32_t A, Bv;  tf2x32(f0, f1, 0u, (uint32_t)ki, A, Bv);
        KK[ii][2 * ki] = A; KK[ii][2 * ki + 1] = Bv;
    }
    __syncthreads();

    // ---- prologue: uniforms for idx 0 (general slot mapping, 704 slots)
    for (int j = tid; j < 704; j += NTHR) {
        int sl = j >> 6;
        int kx = (sl < 9) ? 2 * sl : 18;
        uint32_t m = (sl < 9) ? (uint32_t)(bg * 64 + (j & 63))
                              : (uint32_t)(bg * 128 + (j - 576));
        UNF[0][j] = unifP(KK[0][kx], KK[0][kx + 1], m);
    }

    // ---- prologue: x prefetch for frame 0
    float xf0 = xall[(0 * BB + bg) * HOPC + 0 * SS + row];
    float xf1 = xall[(0 * BB + bg) * HOPC + 1 * SS + row];
    float xf2 = xall[(0 * BB + bg) * HOPC + 2 * SS + row];
    float xf3 = xall[(0 * BB + bg) * HOPC + 3 * SS + row];
    __syncthreads();

    for (int t = 0; t < TT; ++t) {
        // prefetch next frame's x (consumed 4..8 steps from now)
        const int tn = (t + 1 < TT) ? t + 1 : t;
        float xn0 = xall[(tn * BB + bg) * HOPC + 0 * SS + row];
        float xn1 = xall[(tn * BB + bg) * HOPC + 1 * SS + row];
        float xn2 = xall[(tn * BB + bg) * HOPC + 2 * SS + row];
        float xn3 = xall[(tn * BB + bg) * HOPC + 3 * SS + row];

        for (int s = 0; s < 4; ++s) {
            const int idx = t * 4 + s;
            const int p = idx & 1;       // ping-pong parity (H state AND UNF buffer)

            // ======== A (merged with prev OUT): tiny now       [barrier 1]
            if (g == 0) {
                float u0 = UNF[p][row];
                float u1 = UNF[p][64 + row];
                float xv = (s == 0) ? xf0 : (s == 1) ? xf1 : (s == 2) ? xf2 : xf3;
                float xs = noiseu(xv, u0);
                XH[row] = (f16)xs; XH[64 + row] = (f16)xs_old; xs_old = xs;
                SKXH[256 + row] = (f16)noiseu(prevO, u1);
            }
            bar_lds();

            // ======== FW1: tw = tanh(fw_W @ [xsub; s3])            [barrier 2]
            float twv;
            {
                U16 xa, xb;
                xa.u = *(const uint4*)&XH[g * 16];
                xb.u = *(const uint4*)&XH[g * 16 + 8];
                float a = dotU(rF1.w[0], xa, 0.f);
                a = dotU(rF1.w[1], xb, a);
                twv = tanhfast(red8dpp(a));
                if (g == 0) TWH[row] = (f16)twv;
            }
            bar_lds();

            // ======== FW2 + noise(idx+1) slots 0..255              [barrier 3]
            {
                U16 xa; xa.u = *(const uint4*)&TWH[g * 8];
                // next-step uniforms, waves 0-3, hidden under TWH read latency
                if (tid < 256) {
                    int kx = 2 * (tid >> 6);
                    UNF[p ^ 1][tid] = unifP(KK[idx + 1][kx], KK[idx + 1][kx + 1],
                                            (uint32_t)(bg * 64 + (tid & 63)));
                }
                float a = red8dpp(dotU(rF2, xa, 0.f));
                if (g == 0) SKXH[192 + row] = (f16)noiseu(twv * sigmf(a), UNF[p][128 + row]);
            }
            bar_lds();

            // ======== GRU+GLU x3 (2 barriers each)
#define GRU_STEP(RG, XPTR, GI, UH, UG, GOFF, EXTRA)                                         \
            {                                                                               \
                const f16* xin = (XPTR);                                                    \
                U16 xa, xb, xh;                                                             \
                xa.u = *(const uint4*)xin;                                                  \
                xb.u = *(const uint4*)(xin + 8);                                            \
                xh.u = *(const uint4*)&HH[p][GI][g * 8];                                    \
                EXTRA;                                                                      \
                float ai0 = 0, ai1 = 0, ai2 = 0, ah0 = 0, ah1 = 0, ah2 = 0;                 \
                ai0 = dotU(RG.wih[0], xa, ai0); ai0 = dotU(RG.wih[1], xb, ai0);             \
                ai1 = dotU(RG.wih[2], xa, ai1); ai1 = dotU(RG.wih[3], xb, ai1);             \
                ai2 = dotU(RG.wih[4], xa, ai2); ai2 = dotU(RG.wih[5], xb, ai2);             \
                ah0 = dotU(RG.whh[0], xh, ah0);                                             \
                ah1 = dotU(RG.whh[1], xh, ah1);                                             \
                ah2 = dotU(RG.whh[2], xh, ah2);                                             \
                ai0 = red8dpp(ai0); ai1 = red8dpp(ai1); ai2 = red8dpp(ai2);                 \
                ah0 = red8dpp(ah0); ah1 = red8dpp(ah1); ah2 = red8dpp(ah2);                 \
                float hold = Hf[p][GI][row];                                                \
                float r  = sigmf(ai0 + ah0);                                                \
                float z  = sigmf(ai1 + ah1);                                                \
                float nn = tanhfast(ai2 + r * ah2);                                         \
                float hnew = (1.f - z) * nn + z * hold;                                     \
                float hNv = noiseu(hnew, UNF[p][(UH) + row]);                               \
                if (g == 0) {                                                               \
                    Hf[p ^ 1][GI][row] = hnew;                                              \
                    HH[p ^ 1][GI][row] = (f16)hnew;                                         \
                    HNH[row] = (f16)hNv;                                                    \
                }                                                                           \
                bar_lds();                                                                  \
                U16 xg; xg.u = *(const uint4*)&HNH[g * 8];                                  \
                float ag = red8dpp(dotU(RG.glu, xg, 0.f));                                  \
                if (g == 0) SKXH[(GOFF) + row] =                                            \
                    (f16)noiseu(hNv * sigmf(ag), UNF[p][(UG) + row]);                       \
            }                                                                               \
            bar_lds();

            // next-step uniforms slots 256..511 (waves 4-7) and 512..703 (waves 0-2)
#define NOISE_A2 do { if (tid >= 256) {                                                     \
                int kx = 2 * (tid >> 6);                                                    \
                UNF[p ^ 1][tid] = unifP(KK[idx + 1][kx], KK[idx + 1][kx + 1],               \
                                        (uint32_t)(bg * 64 + (tid & 63))); } } while (0)
#define NOISE_B do { int j2 = tid + 512; if (j2 < 704) {                                    \
                int kx = (j2 < 576) ? 16 : 18;                                              \
                uint32_t m2 = (j2 < 576) ? (uint32_t)(bg * 64 + (j2 & 63))                  \
                                         : (uint32_t)(bg * 128 + (j2 - 576));               \
                UNF[p ^ 1][j2] = unifP(KK[idx + 1][kx], KK[idx + 1][kx + 1], m2); } } while (0)

            GRU_STEP(rG1, SKXH + 192 + g * 16, 0, 192, 256, 0, NOISE_A2)
            GRU_STEP(rG2, (g < 4 ? SKXH + g * 16 : SKXH + 256 + (g - 4) * 16), 1, 320, 384, 64, NOISE_B)
            WSK rSK; ldSK(wh + OFF_SKIPD, row, g, rSK);   // prefetch skip_dense (2 phases early)
            GRU_STEP(rG3, (g < 4 ? SKXH + 64 + g * 16 : SKXH + 256 + (g - 4) * 16), 2, 448, 512, 128, ((void)0))
#undef GRU_STEP
#undef NOISE_A2
#undef NOISE_B

            // ======== SKIP: spN = noise(tanh(skip_dense @ SKXH))   [barrier 10]
            float sp0, sp1;
            {
                U16 xs[5];
#pragma unroll
                for (int i = 0; i < 5; ++i) xs[i].u = *(const uint4*)&SKXH[g * 40 + 8 * i];
                float a0 = 0, a1 = 0;
#pragma unroll
                for (int i = 0; i < 5; ++i) {
                    a0 = dotU(rSK.w[i], xs[i], a0);
                    a1 = dotU(rSK.w[5 + i], xs[i], a1);
                }
                sp0 = noiseu(tanhfast(red8dpp(a0)), UNF[p][576 + row]);
                sp1 = noiseu(tanhfast(red8dpp(a1)), UNF[p][640 + row]);
                if (g == 0) { SPNH[row] = (f16)sp0; SPNH[64 + row] = (f16)sp1; }
            }
            bar_lds();

            // ======== SG: skip = spN * sigm(skip_glu @ spN)        [barrier 11]
            {
                U16 xa, xb;
                xa.u = *(const uint4*)&SPNH[g * 16];
                xb.u = *(const uint4*)&SPNH[g * 16 + 8];
                float a0 = dotU(rSG.w[0], xa, 0.f); a0 = dotU(rSG.w[1], xb, a0);
                float a1 = dotU(rSG.w[2], xa, 0.f); a1 = dotU(rSG.w[3], xb, a1);
                a0 = red8dpp(a0); a1 = red8dpp(a1);
                if (g == 0) {
                    SKVH[row]      = (f16)(sp0 * sigmf(a0));
                    SKVH[64 + row] = (f16)(sp1 * sigmf(a1));
                }
            }
            bar_lds();

            // ======== OUT: o = tanh(out_W @ skip)   [no barrier]
            {
                U16 xa, xb;
                xa.u = *(const uint4*)&SKVH[g * 16];
                xb.u = *(const uint4*)&SKVH[g * 16 + 8];
                float a = dotU(rOUT.w[0], xa, 0.f);
                a = dotU(rOUT.w[1], xb, a);
                float o = tanhfast(red8dpp(a));
                prevO = o;
                if (g == 0) outp[bg * (TT * HOPC) + t * HOPC + s * SS + row] = o;
            }
        }
        xf0 = xn0; xf1 = xn1; xf2 = xn2; xf3 = xn3;
    }
}

extern "C" void kernel_launch(void* const* d_in, const int* in_sizes, int n_in,
                              void* d_out, int out_size, void* d_ws, size_t ws_size,
                              hipStream_t stream) {
    const float* features = (const float*)d_in[0];
    const float* gfeat    = (const float*)d_in[1];
    const float* W1       = (const float*)d_in[2];
    const float* ib1      = (const float*)d_in[3];
    const float* W2       = (const float*)d_in[4];
    const float* ib2      = (const float*)d_in[5];

    float* xall = (float*)d_ws;                    // 6.55 MB
    float* fT   = xall + XALL_F32;                 // 6.55 MB
    f16*   wh   = (f16*)(fT + XALL_F32);           // 0.40 MB
    float* outp = (float*)d_out;

    SrcW sw;
    for (int i = 0; i < 14; ++i) sw.p[i] = (const float*)d_in[6 + i];

    hipLaunchKernelGGL(fargan_cvtw, dim3((W_TOTAL + 255) / 256), dim3(256), 0, stream, sw, wh);
    hipLaunchKernelGGL(fargan_tr, dim3(256), dim3(256), 0, stream, features, fT);
    hipLaunchKernelGGL(fargan_frame, dim3(TT * 4), dim3(256), 0, stream,
                       fT, gfeat, W1, ib1, W2, ib2, xall);
    hipLaunchKernelGGL(fargan_seq, dim3(NBLK), dim3(NTHR), 0, stream, xall, wh, outp);
}